// Round 6
// baseline (24981.229 us; speedup 1.0000x reference)
//
#include <hip/hip_runtime.h>
#include <math.h>

#define N_PTS 4096
#define BATCH 4
#define KNN 10
#define NCHUNK 4
#define CHUNK 1024

__device__ __forceinline__ bool better(float v1, int i1, float v2, int i2) {
    return (v1 > v2) || (v1 == v2 && i1 < i2);
}

__device__ __forceinline__ unsigned f2key(float x) {
    unsigned u = __float_as_uint(x);
    return (u & 0x80000000u) ? ~u : (u | 0x80000000u);
}
__device__ __forceinline__ float key2f(unsigned k) {
    unsigned u = (k & 0x80000000u) ? (k & 0x7FFFFFFFu) : ~k;
    return __uint_as_float(u);
}

__device__ __forceinline__ float lrelu(float h) { return (h > 0.f) ? h : 0.2f * h; }

__device__ __forceinline__ void ins11(float v, int c, float (&lv)[11], int (&li)[11]) {
    if (better(v, c, lv[10], li[10])) {
        lv[10] = v; li[10] = c;
        #pragma unroll
        for (int j = 10; j > 0; --j) {
            if (better(lv[j], li[j], lv[j - 1], li[j - 1])) {
                float tv = lv[j]; lv[j] = lv[j - 1]; lv[j - 1] = tv;
                int ti = li[j]; li[j] = li[j - 1]; li[j - 1] = ti;
            }
        }
    }
}

// ---------------- squared norms ----------------
__global__ void sq_kernel(const float* __restrict__ x, int xstr, int D,
                          float* __restrict__ sq) {
    int g = blockIdx.x * blockDim.x + threadIdx.x;
    if (g >= BATCH * N_PTS) return;
    const float* row = x + (long)g * xstr;
    float s = 0.f;
    if ((D & 3) == 0) {
        for (int c = 0; c < D; c += 4) {
            float4 v = *(const float4*)&row[c];
            s += v.x * v.x + v.y * v.y + v.z * v.z + v.w * v.w;
        }
    } else {
        for (int c = 0; c < D; ++c) { float v = row[c]; s += v * v; }
    }
    sq[g] = s;
}

// ---------------- fused knn over a 1024-col chunk ----------------
// Block: 32 rows x 1024 cols. Double-buffered Bs, register prefetch,
// 1 barrier/stage. Candidates fold from GEMM accumulators into per-thread
// top-11 (2 rows); 16-lane pop-merge emits chunk-sorted top-11 to pv/pi.
template <int D, int XSTR>
__global__ __launch_bounds__(256) void knn_kernel(
    const float* __restrict__ x, const float* __restrict__ sq,
    float* __restrict__ pv, int* __restrict__ pi) {
    constexpr int KTOT = (D + 15) & ~15;
    constexpr int NKT = KTOT / 16;
    constexpr int ROWS = 32;
    constexpr int NCT = CHUNK / 128;
    constexpr int NST = NCT * NKT;
    __shared__ float As[KTOT][34];
    __shared__ float Bs[2][16][132];
    __shared__ float sqs[CHUNK];
    int b = blockIdx.z, chunk = blockIdx.y;
    int r0 = blockIdx.x * ROWS;
    int cbase = chunk * CHUNK;
    const float* xb = x + (long)b * N_PTS * XSTR;
    const float* sqb = sq + b * N_PTS;
    int tid = threadIdx.x;
    int tx = tid & 15, ty = tid >> 4;
    for (int e = tid; e < ROWS * KTOT; e += 256) {
        int kk = e % KTOT, row = e / KTOT;
        As[kk][row] = ((D % 16 == 0) || kk < D)
                          ? xb[(long)(r0 + row) * XSTR + kk] : 0.f;
    }
    for (int e = tid; e < CHUNK; e += 256) sqs[e] = sqb[cbase + e];
    float sqr0 = sqb[r0 + ty * 2 + 0];
    float sqr1 = sqb[r0 + ty * 2 + 1];
    // staging thread mapping
    int scol = tid & 127, skh = (tid >> 7) * 8;   // vector path (D%16==0)
    int pcol = tid >> 4, pkk = tid & 15;          // scalar path
    float nb[8];
    // prefetch stage 0 (ct=0, kt=0)
    if (D % 16 == 0) {
        const float* src = &xb[(long)(cbase + scol) * XSTR + skh];
        float4 a = *(const float4*)src;
        float4 bq = *(const float4*)(src + 4);
        nb[0] = a.x; nb[1] = a.y; nb[2] = a.z; nb[3] = a.w;
        nb[4] = bq.x; nb[5] = bq.y; nb[6] = bq.z; nb[7] = bq.w;
    } else {
        #pragma unroll
        for (int i = 0; i < 8; ++i)
            nb[i] = (pkk < D) ? xb[(long)(cbase + pcol + i * 16) * XSTR + pkk] : 0.f;
    }
    float lv0[11], lv1[11]; int li0[11], li1[11];
    #pragma unroll
    for (int j = 0; j < 11; ++j) {
        lv0[j] = -INFINITY; lv1[j] = -INFINITY;
        li0[j] = 0x7FFFFFFF; li1[j] = 0x7FFFFFFF;
    }
    __syncthreads();   // As + sqs staged
    if (D % 16 == 0) {
        #pragma unroll
        for (int i = 0; i < 8; ++i) Bs[0][skh + i][scol] = nb[i];
    } else {
        #pragma unroll
        for (int i = 0; i < 8; ++i) Bs[0][pkk][pcol + i * 16] = nb[i];
    }
    __syncthreads();
    int cur = 0;
    float acc[2][8];
    #pragma unroll 1
    for (int s = 0; s < NST; ++s) {
        int kt = s & (NKT - 1);
        int ct = s / NKT;
        if (kt == 0) {
            #pragma unroll
            for (int j = 0; j < 8; ++j) { acc[0][j] = 0.f; acc[1][j] = 0.f; }
        }
        if (s + 1 < NST) {   // prefetch next stage
            int s1 = s + 1;
            int c0n = cbase + (s1 / NKT) * 128;
            int k0n = (s1 & (NKT - 1)) * 16;
            if (D % 16 == 0) {
                const float* src = &xb[(long)(c0n + scol) * XSTR + k0n + skh];
                float4 a = *(const float4*)src;
                float4 bq = *(const float4*)(src + 4);
                nb[0] = a.x; nb[1] = a.y; nb[2] = a.z; nb[3] = a.w;
                nb[4] = bq.x; nb[5] = bq.y; nb[6] = bq.z; nb[7] = bq.w;
            } else {
                #pragma unroll
                for (int i = 0; i < 8; ++i)
                    nb[i] = (k0n + pkk < D)
                        ? xb[(long)(c0n + pcol + i * 16) * XSTR + k0n + pkk] : 0.f;
            }
        }
        int k0 = kt * 16;
        #pragma unroll
        for (int kk = 0; kk < 16; ++kk) {
            float2 a2 = *(float2*)&As[k0 + kk][ty * 2];
            float bb[8];
            *(float4*)&bb[0] = *(float4*)&Bs[cur][kk][tx * 4];
            *(float4*)&bb[4] = *(float4*)&Bs[cur][kk][64 + tx * 4];
            #pragma unroll
            for (int j = 0; j < 8; ++j) {
                acc[0][j] += a2.x * bb[j];
                acc[1][j] += a2.y * bb[j];
            }
        }
        if (s + 1 < NST) {
            if (D % 16 == 0) {
                #pragma unroll
                for (int i = 0; i < 8; ++i) Bs[cur ^ 1][skh + i][scol] = nb[i];
            } else {
                #pragma unroll
                for (int i = 0; i < 8; ++i) Bs[cur ^ 1][pkk][pcol + i * 16] = nb[i];
            }
        }
        if (kt == NKT - 1) {   // fold this ct's candidates (register-only)
            int ctoff = ct * 128;
            #pragma unroll
            for (int j = 0; j < 4; ++j) {
                int cl0 = ctoff + tx * 4 + j;
                int cl1 = ctoff + 64 + tx * 4 + j;
                float sc0 = sqs[cl0], sc1 = sqs[cl1];
                ins11(2.f * acc[0][j] - sqr0 - sc0, cbase + cl0, lv0, li0);
                ins11(2.f * acc[0][4 + j] - sqr0 - sc1, cbase + cl1, lv0, li0);
                ins11(2.f * acc[1][j] - sqr1 - sc0, cbase + cl0, lv1, li1);
                ins11(2.f * acc[1][4 + j] - sqr1 - sc1, cbase + cl1, lv1, li1);
            }
        }
        __syncthreads();
        cur ^= 1;
    }
    // 16-lane pop-merge: emits chunk top-11, sorted by (value desc, idx asc)
    float rv0 = 0.f, rv1 = 0.f; int ri0 = 0, ri1 = 0;
    #pragma unroll
    for (int r = 0; r < 11; ++r) {
        float bv = lv0[0]; int bi = li0[0];
        #pragma unroll
        for (int off = 8; off > 0; off >>= 1) {
            float ov = __shfl_xor(bv, off);
            int oi = __shfl_xor(bi, off);
            if (better(ov, oi, bv, bi)) { bv = ov; bi = oi; }
        }
        if (li0[0] == bi) {
            #pragma unroll
            for (int j = 0; j < 10; ++j) { lv0[j] = lv0[j + 1]; li0[j] = li0[j + 1]; }
            lv0[10] = -INFINITY; li0[10] = 0x7FFFFFFF;
        }
        if (tx == r) { rv0 = bv; ri0 = bi; }
    }
    #pragma unroll
    for (int r = 0; r < 11; ++r) {
        float bv = lv1[0]; int bi = li1[0];
        #pragma unroll
        for (int off = 8; off > 0; off >>= 1) {
            float ov = __shfl_xor(bv, off);
            int oi = __shfl_xor(bi, off);
            if (better(ov, oi, bv, bi)) { bv = ov; bi = oi; }
        }
        if (li1[0] == bi) {
            #pragma unroll
            for (int j = 0; j < 10; ++j) { lv1[j] = lv1[j + 1]; li1[j] = li1[j + 1]; }
            lv1[10] = -INFINITY; li1[10] = 0x7FFFFFFF;
        }
        if (tx == r) { rv1 = bv; ri1 = bi; }
    }
    if (tx < 11) {
        long row0 = (long)b * N_PTS + r0 + ty * 2;
        long o0 = (row0 * NCHUNK + chunk) * 11 + tx;
        long o1 = ((row0 + 1) * NCHUNK + chunk) * 11 + tx;
        pv[o0] = rv0; pi[o0] = ri0;
        pv[o1] = rv1; pi[o1] = ri1;
    }
}

// ---------------- merge 4 sorted chunk lists -> exact global top-11 -------
__global__ void knnmerge_kernel(const float* __restrict__ pv,
                                const int* __restrict__ pi,
                                int* __restrict__ idxout) {
    int row = blockIdx.x * blockDim.x + threadIdx.x;
    if (row >= BATCH * N_PTS) return;
    const float* v = pv + (long)row * (NCHUNK * 11);
    const int* ii = pi + (long)row * (NCHUNK * 11);
    float hv[NCHUNK]; int hi[NCHUNK]; int hp[NCHUNK];
    #pragma unroll
    for (int c = 0; c < NCHUNK; ++c) {
        hp[c] = 0; hv[c] = v[c * 11]; hi[c] = ii[c * 11];
    }
    #pragma unroll
    for (int t = 0; t < 11; ++t) {
        int cb = 0; float bv = hv[0]; int bi = hi[0];
        #pragma unroll
        for (int c = 1; c < NCHUNK; ++c)
            if (better(hv[c], hi[c], bv, bi)) { cb = c; bv = hv[c]; bi = hi[c]; }
        if (t > 0) idxout[(long)row * KNN + (t - 1)] = bi;
        if (t < 10) {
            int np = ++hp[cb];
            hv[cb] = v[cb * 11 + np]; hi[cb] = ii[cb * 11 + np];
        }
    }
}

// ---------------- edge conv L1 (DIN=3, fused path) ----------------
template <int DIN, int DOUT, int PTS, int TPP>
__global__ __launch_bounds__(256) void edgeconv_kernel(
    const float* __restrict__ x, int xstr, const int* __restrict__ idx,
    const float* __restrict__ w, const float* __restrict__ gamma,
    const float* __restrict__ beta, float* __restrict__ out, int outoff) {
    constexpr int DP = DIN + 1;
    constexpr int C2 = 2 * DIN;
    __shared__ float ctr[PTS][DP];
    __shared__ float nm[PTS][KNN][DP];
    int p0 = blockIdx.x * PTS;
    for (int e = threadIdx.x; e < PTS * DIN; e += 256) {
        int p = e / DIN, c = e - p * DIN;
        ctr[p][c] = x[(long)(p0 + p) * xstr + c];
    }
    __syncthreads();
    for (int e = threadIdx.x; e < PTS * KNN * DIN; e += 256) {
        int p = e / (KNN * DIN);
        int rem = e - p * (KNN * DIN);
        int kk = rem / DIN, c = rem - kk * DIN;
        int g = p0 + p;
        int nb = (g & ~(N_PTS - 1)) + idx[(long)g * KNN + kk];
        nm[p][kk][c] = x[(long)nb * xstr + c] - ctr[p][c];
    }
    __syncthreads();
    int p = threadIdx.x / TPP;
    int og = (threadIdx.x % TPP) * 4;
    float gs[4], bt[4];
    #pragma unroll
    for (int j = 0; j < 4; ++j) {
        gs[j] = gamma[og + j] / sqrtf(1.f + 1e-5f);
        bt[j] = beta[og + j];
    }
    float base[4] = {0.f, 0.f, 0.f, 0.f};
    for (int c = 0; c < DIN; ++c) {
        float cv = ctr[p][c];
        #pragma unroll
        for (int j = 0; j < 4; ++j) base[j] += cv * w[(og + j) * C2 + DIN + c];
    }
    float acc[KNN][4];
    #pragma unroll
    for (int kk = 0; kk < KNN; ++kk)
        #pragma unroll
        for (int j = 0; j < 4; ++j) acc[kk][j] = base[j];
    for (int c = 0; c < DIN; ++c) {
        float w4[4];
        #pragma unroll
        for (int j = 0; j < 4; ++j) w4[j] = w[(og + j) * C2 + c];
        #pragma unroll
        for (int kk = 0; kk < KNN; ++kk) {
            float nv = nm[p][kk][c];
            #pragma unroll
            for (int j = 0; j < 4; ++j) acc[kk][j] += nv * w4[j];
        }
    }
    float best[4] = {-INFINITY, -INFINITY, -INFINITY, -INFINITY};
    #pragma unroll
    for (int kk = 0; kk < KNN; ++kk)
        #pragma unroll
        for (int j = 0; j < 4; ++j)
            best[j] = fmaxf(best[j], lrelu(acc[kk][j] * gs[j] + bt[j]));
    #pragma unroll
    for (int j = 0; j < 4; ++j)
        out[(long)(p0 + p) * 512 + outoff + og + j] = best[j];
}

// ---------------- uv GEMM: uv[r][j] = sum_k x[r][k] * Bcat[k][j] ----------
template <int DIN, int DOUT>
__global__ __launch_bounds__(256) void uvgemm_kernel(
    const float* __restrict__ x, int xoff, const float* __restrict__ w,
    float* __restrict__ uv) {
    constexpr int NC = 2 * DOUT;
    __shared__ float As[16][132];
    __shared__ float Bs[16][132];
    int r0 = blockIdx.y * 128;
    int c0 = blockIdx.x * 128;
    int tx = threadIdx.x & 15, ty = threadIdx.x >> 4;
    float acc[8][8] = {};
    #pragma unroll 1
    for (int kt = 0; kt < DIN / 16; ++kt) {
        int k0 = kt * 16;
        for (int e = threadIdx.x; e < 2048; e += 256) {
            int kk = e & 15, r = e >> 4;
            As[kk][r] = x[(long)(r0 + r) * 512 + xoff + k0 + kk];
            int jg = c0 + r;
            Bs[kk][r] = (jg < DOUT) ? w[(long)jg * (2 * DIN) + k0 + kk]
                                    : w[(long)(jg - DOUT) * (2 * DIN) + DIN + k0 + kk];
        }
        __syncthreads();
        #pragma unroll
        for (int kk = 0; kk < 16; ++kk) {
            float a[8], bb[8];
            *(float4*)&a[0] = *(float4*)&As[kk][ty * 8];
            *(float4*)&a[4] = *(float4*)&As[kk][ty * 8 + 4];
            *(float4*)&bb[0] = *(float4*)&Bs[kk][tx * 4];
            *(float4*)&bb[4] = *(float4*)&Bs[kk][64 + tx * 4];
            #pragma unroll
            for (int i = 0; i < 8; ++i)
                #pragma unroll
                for (int j = 0; j < 8; ++j) acc[i][j] += a[i] * bb[j];
        }
        __syncthreads();
    }
    int cb0 = c0 + tx * 4;
    int cb1 = c0 + 64 + tx * 4;
    #pragma unroll
    for (int i = 0; i < 8; ++i) {
        int r = r0 + ty * 8 + i;
        *(float4*)&uv[(long)r * NC + cb0] = *(float4*)&acc[i][0];
        *(float4*)&uv[(long)r * NC + cb1] = *(float4*)&acc[i][4];
    }
}

// ---------------- edge max epilogue: h = u[nb] - u[n] + v[n] --------------
template <int DOUT>
__global__ __launch_bounds__(256) void edgemax_kernel(
    const float* __restrict__ uv, const int* __restrict__ idx,
    const float* __restrict__ gamma, const float* __restrict__ beta,
    float* __restrict__ out, int outoff) {
    constexpr int NC = 2 * DOUT;
    constexpr int TPP = DOUT / 4;
    constexpr int TP = 256 / TPP;
    __shared__ int sidx[TP][KNN];
    int p0 = blockIdx.x * TP;
    for (int e = threadIdx.x; e < TP * KNN; e += 256)
        sidx[e / KNN][e % KNN] = idx[(long)(p0 + e / KNN) * KNN + (e % KNN)];
    __syncthreads();
    int p = threadIdx.x / TPP;
    int og = (threadIdx.x % TPP) * 4;
    int g = p0 + p;
    int base_pt = g & ~(N_PTS - 1);
    const float* rowg = uv + (long)g * NC;
    float4 u_n = *(const float4*)&rowg[og];
    float4 v_n = *(const float4*)&rowg[DOUT + og];
    float c0 = v_n.x - u_n.x, c1 = v_n.y - u_n.y;
    float c2 = v_n.z - u_n.z, c3 = v_n.w - u_n.w;
    const float rs = 1.f / sqrtf(1.f + 1e-5f);
    float gs0 = gamma[og + 0] * rs, gs1 = gamma[og + 1] * rs;
    float gs2 = gamma[og + 2] * rs, gs3 = gamma[og + 3] * rs;
    float bt0 = beta[og + 0], bt1 = beta[og + 1];
    float bt2 = beta[og + 2], bt3 = beta[og + 3];
    float b0 = -INFINITY, b1 = -INFINITY, b2 = -INFINITY, b3 = -INFINITY;
    #pragma unroll
    for (int kk = 0; kk < KNN; ++kk) {
        int nb = base_pt + sidx[p][kk];
        float4 ub = *(const float4*)&uv[(long)nb * NC + og];
        b0 = fmaxf(b0, lrelu((ub.x + c0) * gs0 + bt0));
        b1 = fmaxf(b1, lrelu((ub.y + c1) * gs1 + bt1));
        b2 = fmaxf(b2, lrelu((ub.z + c2) * gs2 + bt2));
        b3 = fmaxf(b3, lrelu((ub.w + c3) * gs3 + bt3));
    }
    float4 o4; o4.x = b0; o4.y = b1; o4.z = b2; o4.w = b3;
    *(float4*)&out[(long)g * 512 + outoff + og] = o4;
}

// ---------------- init h5 key buffer ----------------
__global__ void init_h5_kernel(unsigned* __restrict__ h5key) {
    int t = blockIdx.x * blockDim.x + threadIdx.x;
    if (t < BATCH * 1024) h5key[t] = 0u;
}

// ---------------- w5 GEMM + BN + lrelu + max over n, 128x128 tile ---------
__global__ __launch_bounds__(256) void w5max_kernel(
    const float* __restrict__ cat, const float* __restrict__ w5,
    const float* __restrict__ g5, const float* __restrict__ b5,
    unsigned* __restrict__ h5key) {
    __shared__ float As[16][132];
    __shared__ float Bs[16][132];
    int b = blockIdx.z;
    int n0 = blockIdx.y * 128, o0 = blockIdx.x * 128;
    int tx = threadIdx.x & 15, ty = threadIdx.x >> 4;
    const float* A = cat + (long)b * N_PTS * 512;
    float acc[8][8] = {};
    for (int kt = 0; kt < 32; ++kt) {
        int k0 = kt * 16;
        for (int e = threadIdx.x; e < 2048; e += 256) {
            int kk = e & 15, r = e >> 4;
            As[kk][r] = A[(long)(n0 + r) * 512 + k0 + kk];
            Bs[kk][r] = w5[(long)(o0 + r) * 512 + k0 + kk];
        }
        __syncthreads();
        #pragma unroll
        for (int kk = 0; kk < 16; ++kk) {
            float a[8], bb[8];
            *(float4*)&a[0] = *(float4*)&As[kk][ty * 8];
            *(float4*)&a[4] = *(float4*)&As[kk][ty * 8 + 4];
            *(float4*)&bb[0] = *(float4*)&Bs[kk][tx * 4];
            *(float4*)&bb[4] = *(float4*)&Bs[kk][64 + tx * 4];
            #pragma unroll
            for (int i = 0; i < 8; ++i)
                #pragma unroll
                for (int j = 0; j < 8; ++j) acc[i][j] += a[i] * bb[j];
        }
        __syncthreads();
    }
    float colmax[8];
    #pragma unroll
    for (int j = 0; j < 8; ++j) {
        int col_local = (j < 4) ? (tx * 4 + j) : (64 + tx * 4 + (j - 4));
        int o = o0 + col_local;
        float gsc = g5[o] / sqrtf(1.f + 1e-5f);
        float bto = b5[o];
        float m = -INFINITY;
        #pragma unroll
        for (int i = 0; i < 8; ++i)
            m = fmaxf(m, lrelu(acc[i][j] * gsc + bto));
        colmax[j] = m;
    }
    __syncthreads();
    float* red = &As[0][0];
    #pragma unroll
    for (int j = 0; j < 8; ++j) {
        int col_local = (j < 4) ? (tx * 4 + j) : (64 + tx * 4 + (j - 4));
        red[ty * 128 + col_local] = colmax[j];
    }
    __syncthreads();
    if (threadIdx.x < 128) {
        int col = threadIdx.x;
        float m = -INFINITY;
        #pragma unroll
        for (int t = 0; t < 16; ++t) m = fmaxf(m, red[t * 128 + col]);
        atomicMax(&h5key[b * 1024 + o0 + col], f2key(m));
    }
}

// ---------------- FC head ----------------
__global__ void fc1_kernel(const unsigned* __restrict__ h5key,
                           const float* __restrict__ fw1,
                           const float* __restrict__ fg1,
                           const float* __restrict__ fbt1,
                           float* __restrict__ f1) {
    int o = blockIdx.x * 256 + threadIdx.x;
    int b = blockIdx.y;
    if (o >= 512) return;
    float s = 0.f;
    for (int c = 0; c < 1024; ++c)
        s += key2f(h5key[b * 1024 + c]) * fw1[o * 1024 + c];
    float h = s * (fg1[o] / sqrtf(1.f + 1e-5f)) + fbt1[o];
    f1[b * 512 + o] = lrelu(h);
}

__global__ void fc2_kernel(const float* __restrict__ f1,
                           const float* __restrict__ fw2,
                           const float* __restrict__ fb2,
                           const float* __restrict__ fg2,
                           const float* __restrict__ fbt2,
                           float* __restrict__ f2) {
    int o = threadIdx.x;
    int b = blockIdx.x;
    float s = fb2[o];
    for (int c = 0; c < 512; ++c) s += f1[b * 512 + c] * fw2[o * 512 + c];
    float h = s * (fg2[o] / sqrtf(1.f + 1e-5f)) + fbt2[o];
    f2[b * 256 + o] = lrelu(h);
}

__global__ void fc3_kernel(const float* __restrict__ f2,
                           const float* __restrict__ fw3,
                           const float* __restrict__ fb3,
                           float* __restrict__ out) {
    int t = threadIdx.x;
    if (t >= BATCH * 3) return;
    int b = t / 3, o = t - b * 3;
    float s = fb3[o];
    for (int c = 0; c < 256; ++c) s += f2[b * 256 + c] * fw3[o * 256 + c];
    out[t] = s;
}

extern "C" void kernel_launch(void* const* d_in, const int* in_sizes, int n_in,
                              void* d_out, int out_size, void* d_ws, size_t ws_size,
                              hipStream_t stream) {
    const float* points = (const float*)d_in[0];
    const float* w1 = (const float*)d_in[2];
    const float* g1 = (const float*)d_in[3];
    const float* b1 = (const float*)d_in[4];
    const float* w2 = (const float*)d_in[5];
    const float* g2 = (const float*)d_in[6];
    const float* b2 = (const float*)d_in[7];
    const float* w3 = (const float*)d_in[8];
    const float* g3 = (const float*)d_in[9];
    const float* b3 = (const float*)d_in[10];
    const float* w4 = (const float*)d_in[11];
    const float* g4 = (const float*)d_in[12];
    const float* b4 = (const float*)d_in[13];
    const float* w5 = (const float*)d_in[14];
    const float* g5 = (const float*)d_in[15];
    const float* b5 = (const float*)d_in[16];
    const float* fw1 = (const float*)d_in[17];
    const float* fg1 = (const float*)d_in[18];
    const float* fbt1 = (const float*)d_in[19];
    const float* fw2 = (const float*)d_in[20];
    const float* fb2 = (const float*)d_in[21];
    const float* fg2 = (const float*)d_in[22];
    const float* fbt2 = (const float*)d_in[23];
    const float* fw3 = (const float*)d_in[24];
    const float* fb3 = (const float*)d_in[25];

    float* ws = (float*)d_ws;
    float* cat = ws;                                     // 4*4096*512
    float* sq = cat + (long)BATCH * N_PTS * 512;         // 16384
    unsigned* h5key = (unsigned*)(sq + BATCH * N_PTS);   // 4096
    float* f1 = (float*)(h5key + BATCH * 1024);          // 2048
    float* f2 = f1 + BATCH * 512;                        // 1024
    int* idxbuf = (int*)(f2 + BATCH * 256);              // 4*4096*10
    float* uv = (float*)(idxbuf + (long)BATCH * N_PTS * KNN); // 4*4096*512
    float* pvb = uv + (long)BATCH * N_PTS * 512;         // 4*4096*4*11
    int* pib = (int*)(pvb + (long)BATCH * N_PTS * NCHUNK * 11);

    dim3 knng(N_PTS / 32, NCHUNK, BATCH);

    // layer 1: points(3) -> o1 (64) at cat+0
    sq_kernel<<<64, 256, 0, stream>>>(points, 3, 3, sq);
    knn_kernel<3, 3><<<knng, 256, 0, stream>>>(points, sq, pvb, pib);
    knnmerge_kernel<<<64, 256, 0, stream>>>(pvb, pib, idxbuf);
    edgeconv_kernel<3, 64, 16, 16><<<N_PTS * BATCH / 16, 256, 0, stream>>>(
        points, 3, idxbuf, w1, g1, b1, cat, 0);

    // layer 2: o1(64) -> o2 (64) at cat+64
    sq_kernel<<<64, 256, 0, stream>>>(cat + 0, 512, 64, sq);
    knn_kernel<64, 512><<<knng, 256, 0, stream>>>(cat + 0, sq, pvb, pib);
    knnmerge_kernel<<<64, 256, 0, stream>>>(pvb, pib, idxbuf);
    uvgemm_kernel<64, 64><<<dim3(1, 128), 256, 0, stream>>>(cat, 0, w2, uv);
    edgemax_kernel<64><<<1024, 256, 0, stream>>>(uv, idxbuf, g2, b2, cat, 64);

    // layer 3: o2(64) -> o3 (128) at cat+128
    sq_kernel<<<64, 256, 0, stream>>>(cat + 64, 512, 64, sq);
    knn_kernel<64, 512><<<knng, 256, 0, stream>>>(cat + 64, sq, pvb, pib);
    knnmerge_kernel<<<64, 256, 0, stream>>>(pvb, pib, idxbuf);
    uvgemm_kernel<64, 128><<<dim3(2, 128), 256, 0, stream>>>(cat, 64, w3, uv);
    edgemax_kernel<128><<<2048, 256, 0, stream>>>(uv, idxbuf, g3, b3, cat, 128);

    // layer 4: o3(128) -> o4 (256) at cat+256
    sq_kernel<<<64, 256, 0, stream>>>(cat + 128, 512, 128, sq);
    knn_kernel<128, 512><<<knng, 256, 0, stream>>>(cat + 128, sq, pvb, pib);
    knnmerge_kernel<<<64, 256, 0, stream>>>(pvb, pib, idxbuf);
    uvgemm_kernel<128, 256><<<dim3(4, 128), 256, 0, stream>>>(cat, 128, w4, uv);
    edgemax_kernel<256><<<4096, 256, 0, stream>>>(uv, idxbuf, g4, b4, cat, 256);

    // global feature
    init_h5_kernel<<<16, 256, 0, stream>>>(h5key);
    w5max_kernel<<<dim3(8, 32, BATCH), 256, 0, stream>>>(cat, w5, g5, b5, h5key);

    // FC head
    fc1_kernel<<<dim3(2, BATCH), 256, 0, stream>>>(h5key, fw1, fg1, fbt1, f1);
    fc2_kernel<<<BATCH, 256, 0, stream>>>(f1, fw2, fb2, fg2, fbt2, f2);
    fc3_kernel<<<1, 64, 0, stream>>>(f2, fw3, fb3, (float*)d_out);
}

// Round 7
// 11747.072 us; speedup vs baseline: 2.1266x; 2.1266x over previous
//
#include <hip/hip_runtime.h>
#include <math.h>

#define N_PTS 4096
#define BATCH 4
#define KNN 10
#define NCHUNK 4
#define CHUNK 1024

__device__ __forceinline__ bool better(float v1, int i1, float v2, int i2) {
    return (v1 > v2) || (v1 == v2 && i1 < i2);
}

__device__ __forceinline__ unsigned f2key(float x) {
    unsigned u = __float_as_uint(x);
    return (u & 0x80000000u) ? ~u : (u | 0x80000000u);
}
__device__ __forceinline__ float key2f(unsigned k) {
    unsigned u = (k & 0x80000000u) ? (k & 0x7FFFFFFFu) : ~k;
    return __uint_as_float(u);
}

__device__ __forceinline__ float lrelu(float h) { return (h > 0.f) ? h : 0.2f * h; }

__device__ __forceinline__ void ins11(float v, int c, float (&lv)[11], int (&li)[11]) {
    if (better(v, c, lv[10], li[10])) {
        lv[10] = v; li[10] = c;
        #pragma unroll
        for (int j = 10; j > 0; --j) {
            if (better(lv[j], li[j], lv[j - 1], li[j - 1])) {
                float tv = lv[j]; lv[j] = lv[j - 1]; lv[j - 1] = tv;
                int ti = li[j]; li[j] = li[j - 1]; li[j - 1] = ti;
            }
        }
    }
}

// ---------------- squared norms ----------------
__global__ void sq_kernel(const float* __restrict__ x, int xstr, int D,
                          float* __restrict__ sq) {
    int g = blockIdx.x * blockDim.x + threadIdx.x;
    if (g >= BATCH * N_PTS) return;
    const float* row = x + (long)g * xstr;
    float s = 0.f;
    if ((D & 3) == 0) {
        for (int c = 0; c < D; c += 4) {
            float4 v = *(const float4*)&row[c];
            s += v.x * v.x + v.y * v.y + v.z * v.z + v.w * v.w;
        }
    } else {
        for (int c = 0; c < D; ++c) { float v = row[c]; s += v * v; }
    }
    sq[g] = s;
}

// ---------------- fused knn over a 1024-col chunk ----------------
// Block: 32 rows x 1024 cols. Thread = 1 row x 16 contiguous cols (acc[16],
// ONE top-11 list -> no spill). Double-buffered Bs (+4/16 swizzle: bank-
// conflict-free, 16B-aligned), 1 barrier/stage. 8-lane pop-merge emits the
// 11-slot sorted chunk list to pv/pi.
template <int D, int XSTR>
__global__ __launch_bounds__(256) void knn_kernel(
    const float* __restrict__ x, const float* __restrict__ sq,
    float* __restrict__ pv, int* __restrict__ pi) {
    constexpr int KTOT = (D + 15) & ~15;
    constexpr int NKT = KTOT / 16;
    constexpr int ROWS = 32;
    constexpr int NCT = CHUNK / 128;
    constexpr int NST = NCT * NKT;
    __shared__ float As[ROWS][KTOT + 4];
    __shared__ float Bs[2][16][156];
    __shared__ float sqs[CHUNK];
    int b = blockIdx.z, chunk = blockIdx.y;
    int r0 = blockIdx.x * ROWS;
    int cbase = chunk * CHUNK;
    const float* xb = x + (long)b * N_PTS * XSTR;
    const float* sqb = sq + b * N_PTS;
    int tid = threadIdx.x;
    int r = tid >> 3, s = tid & 7;
    // stage A rows (row-major, coalesced)
    if (D % 16 == 0) {
        for (int e = tid; e < ROWS * KTOT / 4; e += 256) {
            int c4 = e % (KTOT / 4), row = e / (KTOT / 4);
            *(float4*)&As[row][c4 * 4] =
                *(const float4*)&xb[(long)(r0 + row) * XSTR + c4 * 4];
        }
    } else {
        for (int e = tid; e < ROWS * KTOT; e += 256) {
            int kk = e % KTOT, row = e / KTOT;
            As[row][kk] = (kk < D) ? xb[(long)(r0 + row) * XSTR + kk] : 0.f;
        }
    }
    for (int e = tid; e < CHUNK; e += 256) sqs[e] = sqb[cbase + e];
    float sqr = sqb[r0 + r];
    // staging thread mapping
    int scol = tid & 127, skh = (tid >> 7) * 8;     // vector path (D%16==0)
    int scphys = scol + ((scol >> 4) << 2);
    int pcol = tid >> 4, pkk = tid & 15;            // scalar path
    float nb[8];
    // prefetch stage 0 (ct=0, kt=0)
    if (D % 16 == 0) {
        const float* src = &xb[(long)(cbase + scol) * XSTR + skh];
        float4 a = *(const float4*)src;
        float4 bq = *(const float4*)(src + 4);
        nb[0] = a.x; nb[1] = a.y; nb[2] = a.z; nb[3] = a.w;
        nb[4] = bq.x; nb[5] = bq.y; nb[6] = bq.z; nb[7] = bq.w;
    } else {
        #pragma unroll
        for (int i = 0; i < 8; ++i)
            nb[i] = (pkk < D) ? xb[(long)(cbase + pcol + i * 16) * XSTR + pkk] : 0.f;
    }
    float lv[11]; int li[11];
    #pragma unroll
    for (int j = 0; j < 11; ++j) { lv[j] = -INFINITY; li[j] = 0x7FFFFFFF; }
    __syncthreads();   // As + sqs staged
    if (D % 16 == 0) {
        #pragma unroll
        for (int i = 0; i < 8; ++i) Bs[0][skh + i][scphys] = nb[i];
    } else {
        #pragma unroll
        for (int i = 0; i < 8; ++i) Bs[0][pkk][pcol + i * 20] = nb[i];
    }
    __syncthreads();
    int cur = 0;
    int sb = s * 20;
    float acc[16];
    #pragma unroll 1
    for (int st = 0; st < NST; ++st) {
        int kt = st & (NKT - 1);
        int ct = st / NKT;
        if (kt == 0) {
            #pragma unroll
            for (int j = 0; j < 16; ++j) acc[j] = 0.f;
        }
        if (st + 1 < NST) {   // prefetch next stage
            int s1 = st + 1;
            int c0n = cbase + (s1 / NKT) * 128;
            int k0n = (s1 & (NKT - 1)) * 16;
            if (D % 16 == 0) {
                const float* src = &xb[(long)(c0n + scol) * XSTR + k0n + skh];
                float4 a = *(const float4*)src;
                float4 bq = *(const float4*)(src + 4);
                nb[0] = a.x; nb[1] = a.y; nb[2] = a.z; nb[3] = a.w;
                nb[4] = bq.x; nb[5] = bq.y; nb[6] = bq.z; nb[7] = bq.w;
            } else {
                #pragma unroll
                for (int i = 0; i < 8; ++i)
                    nb[i] = (k0n + pkk < D)
                        ? xb[(long)(c0n + pcol + i * 16) * XSTR + k0n + pkk] : 0.f;
            }
        }
        int k0 = kt * 16;
        #pragma unroll
        for (int m = 0; m < 4; ++m) {
            float4 a4 = *(float4*)&As[r][k0 + 4 * m];
            float av[4] = {a4.x, a4.y, a4.z, a4.w};
            #pragma unroll
            for (int e = 0; e < 4; ++e) {
                int kk = 4 * m + e;
                float bb[16];
                *(float4*)&bb[0]  = *(float4*)&Bs[cur][kk][sb];
                *(float4*)&bb[4]  = *(float4*)&Bs[cur][kk][sb + 4];
                *(float4*)&bb[8]  = *(float4*)&Bs[cur][kk][sb + 8];
                *(float4*)&bb[12] = *(float4*)&Bs[cur][kk][sb + 12];
                float a = av[e];
                #pragma unroll
                for (int j = 0; j < 16; ++j) acc[j] += a * bb[j];
            }
        }
        if (st + 1 < NST) {
            if (D % 16 == 0) {
                #pragma unroll
                for (int i = 0; i < 8; ++i) Bs[cur ^ 1][skh + i][scphys] = nb[i];
            } else {
                #pragma unroll
                for (int i = 0; i < 8; ++i) Bs[cur ^ 1][pkk][pcol + i * 20] = nb[i];
            }
        }
        if (kt == NKT - 1) {   // fold this ct's 16 candidates (register-only)
            int ctoff = ct * 128 + s * 16;
            #pragma unroll
            for (int j = 0; j < 16; ++j) {
                int cl = ctoff + j;
                ins11(2.f * acc[j] - sqr - sqs[cl], cbase + cl, lv, li);
            }
        }
        __syncthreads();
        cur ^= 1;
    }
    // 8-lane pop-merge: 11 rounds emit the chunk's sorted top-11
    // slot q -> lane q&7 (rv0 for q<8, rv1 for q>=8)
    float rv0 = 0.f, rv1 = 0.f; int ri0 = 0, ri1 = 0;
    #pragma unroll
    for (int rr = 0; rr < 11; ++rr) {
        float bv = lv[0]; int bi = li[0];
        #pragma unroll
        for (int off = 4; off > 0; off >>= 1) {
            float ov = __shfl_xor(bv, off);
            int oi = __shfl_xor(bi, off);
            if (better(ov, oi, bv, bi)) { bv = ov; bi = oi; }
        }
        if (li[0] == bi) {
            #pragma unroll
            for (int j = 0; j < 10; ++j) { lv[j] = lv[j + 1]; li[j] = li[j + 1]; }
            lv[10] = -INFINITY; li[10] = 0x7FFFFFFF;
        }
        if ((rr & 7) == s) {
            if (rr < 8) { rv0 = bv; ri0 = bi; } else { rv1 = bv; ri1 = bi; }
        }
    }
    long rowg = (long)b * N_PTS + r0 + r;
    long o = (rowg * NCHUNK + chunk) * 11;
    pv[o + s] = rv0; pi[o + s] = ri0;
    if (s < 3) { pv[o + 8 + s] = rv1; pi[o + 8 + s] = ri1; }
}

// ---------------- merge 4 sorted chunk lists -> exact global top-11 -------
__global__ void knnmerge_kernel(const float* __restrict__ pv,
                                const int* __restrict__ pi,
                                int* __restrict__ idxout) {
    int row = blockIdx.x * blockDim.x + threadIdx.x;
    if (row >= BATCH * N_PTS) return;
    const float* v = pv + (long)row * (NCHUNK * 11);
    const int* ii = pi + (long)row * (NCHUNK * 11);
    float hv[NCHUNK]; int hi[NCHUNK]; int hp[NCHUNK];
    #pragma unroll
    for (int c = 0; c < NCHUNK; ++c) {
        hp[c] = 0; hv[c] = v[c * 11]; hi[c] = ii[c * 11];
    }
    #pragma unroll
    for (int t = 0; t < 11; ++t) {
        int cb = 0; float bv = hv[0]; int bi = hi[0];
        #pragma unroll
        for (int c = 1; c < NCHUNK; ++c)
            if (better(hv[c], hi[c], bv, bi)) { cb = c; bv = hv[c]; bi = hi[c]; }
        if (t > 0) idxout[(long)row * KNN + (t - 1)] = bi;
        if (t < 10) {
            int np = ++hp[cb];
            hv[cb] = v[cb * 11 + np]; hi[cb] = ii[cb * 11 + np];
        }
    }
}

// ---------------- edge conv L1 (DIN=3, fused path) ----------------
template <int DIN, int DOUT, int PTS, int TPP>
__global__ __launch_bounds__(256) void edgeconv_kernel(
    const float* __restrict__ x, int xstr, const int* __restrict__ idx,
    const float* __restrict__ w, const float* __restrict__ gamma,
    const float* __restrict__ beta, float* __restrict__ out, int outoff) {
    constexpr int DP = DIN + 1;
    constexpr int C2 = 2 * DIN;
    __shared__ float ctr[PTS][DP];
    __shared__ float nm[PTS][KNN][DP];
    int p0 = blockIdx.x * PTS;
    for (int e = threadIdx.x; e < PTS * DIN; e += 256) {
        int p = e / DIN, c = e - p * DIN;
        ctr[p][c] = x[(long)(p0 + p) * xstr + c];
    }
    __syncthreads();
    for (int e = threadIdx.x; e < PTS * KNN * DIN; e += 256) {
        int p = e / (KNN * DIN);
        int rem = e - p * (KNN * DIN);
        int kk = rem / DIN, c = rem - kk * DIN;
        int g = p0 + p;
        int nb = (g & ~(N_PTS - 1)) + idx[(long)g * KNN + kk];
        nm[p][kk][c] = x[(long)nb * xstr + c] - ctr[p][c];
    }
    __syncthreads();
    int p = threadIdx.x / TPP;
    int og = (threadIdx.x % TPP) * 4;
    float gs[4], bt[4];
    #pragma unroll
    for (int j = 0; j < 4; ++j) {
        gs[j] = gamma[og + j] / sqrtf(1.f + 1e-5f);
        bt[j] = beta[og + j];
    }
    float base[4] = {0.f, 0.f, 0.f, 0.f};
    for (int c = 0; c < DIN; ++c) {
        float cv = ctr[p][c];
        #pragma unroll
        for (int j = 0; j < 4; ++j) base[j] += cv * w[(og + j) * C2 + DIN + c];
    }
    float acc[KNN][4];
    #pragma unroll
    for (int kk = 0; kk < KNN; ++kk)
        #pragma unroll
        for (int j = 0; j < 4; ++j) acc[kk][j] = base[j];
    for (int c = 0; c < DIN; ++c) {
        float w4[4];
        #pragma unroll
        for (int j = 0; j < 4; ++j) w4[j] = w[(og + j) * C2 + c];
        #pragma unroll
        for (int kk = 0; kk < KNN; ++kk) {
            float nv = nm[p][kk][c];
            #pragma unroll
            for (int j = 0; j < 4; ++j) acc[kk][j] += nv * w4[j];
        }
    }
    float best[4] = {-INFINITY, -INFINITY, -INFINITY, -INFINITY};
    #pragma unroll
    for (int kk = 0; kk < KNN; ++kk)
        #pragma unroll
        for (int j = 0; j < 4; ++j)
            best[j] = fmaxf(best[j], lrelu(acc[kk][j] * gs[j] + bt[j]));
    #pragma unroll
    for (int j = 0; j < 4; ++j)
        out[(long)(p0 + p) * 512 + outoff + og + j] = best[j];
}

// ---------------- uv GEMM: uv[r][j] = sum_k x[r][k] * Bcat[k][j] ----------
template <int DIN, int DOUT>
__global__ __launch_bounds__(256) void uvgemm_kernel(
    const float* __restrict__ x, int xoff, const float* __restrict__ w,
    float* __restrict__ uv) {
    constexpr int NC = 2 * DOUT;
    __shared__ float As[16][132];
    __shared__ float Bs[16][132];
    int r0 = blockIdx.y * 128;
    int c0 = blockIdx.x * 128;
    int tx = threadIdx.x & 15, ty = threadIdx.x >> 4;
    float acc[8][8] = {};
    #pragma unroll 1
    for (int kt = 0; kt < DIN / 16; ++kt) {
        int k0 = kt * 16;
        for (int e = threadIdx.x; e < 2048; e += 256) {
            int kk = e & 15, r = e >> 4;
            As[kk][r] = x[(long)(r0 + r) * 512 + xoff + k0 + kk];
            int jg = c0 + r;
            Bs[kk][r] = (jg < DOUT) ? w[(long)jg * (2 * DIN) + k0 + kk]
                                    : w[(long)(jg - DOUT) * (2 * DIN) + DIN + k0 + kk];
        }
        __syncthreads();
        #pragma unroll
        for (int kk = 0; kk < 16; ++kk) {
            float a[8], bb[8];
            *(float4*)&a[0] = *(float4*)&As[kk][ty * 8];
            *(float4*)&a[4] = *(float4*)&As[kk][ty * 8 + 4];
            *(float4*)&bb[0] = *(float4*)&Bs[kk][tx * 4];
            *(float4*)&bb[4] = *(float4*)&Bs[kk][64 + tx * 4];
            #pragma unroll
            for (int i = 0; i < 8; ++i)
                #pragma unroll
                for (int j = 0; j < 8; ++j) acc[i][j] += a[i] * bb[j];
        }
        __syncthreads();
    }
    int cb0 = c0 + tx * 4;
    int cb1 = c0 + 64 + tx * 4;
    #pragma unroll
    for (int i = 0; i < 8; ++i) {
        int r = r0 + ty * 8 + i;
        *(float4*)&uv[(long)r * NC + cb0] = *(float4*)&acc[i][0];
        *(float4*)&uv[(long)r * NC + cb1] = *(float4*)&acc[i][4];
    }
}

// ---------------- edge max epilogue: h = u[nb] - u[n] + v[n] --------------
template <int DOUT>
__global__ __launch_bounds__(256) void edgemax_kernel(
    const float* __restrict__ uv, const int* __restrict__ idx,
    const float* __restrict__ gamma, const float* __restrict__ beta,
    float* __restrict__ out, int outoff) {
    constexpr int NC = 2 * DOUT;
    constexpr int TPP = DOUT / 4;
    constexpr int TP = 256 / TPP;
    __shared__ int sidx[TP][KNN];
    int p0 = blockIdx.x * TP;
    for (int e = threadIdx.x; e < TP * KNN; e += 256)
        sidx[e / KNN][e % KNN] = idx[(long)(p0 + e / KNN) * KNN + (e % KNN)];
    __syncthreads();
    int p = threadIdx.x / TPP;
    int og = (threadIdx.x % TPP) * 4;
    int g = p0 + p;
    int base_pt = g & ~(N_PTS - 1);
    const float* rowg = uv + (long)g * NC;
    float4 u_n = *(const float4*)&rowg[og];
    float4 v_n = *(const float4*)&rowg[DOUT + og];
    float c0 = v_n.x - u_n.x, c1 = v_n.y - u_n.y;
    float c2 = v_n.z - u_n.z, c3 = v_n.w - u_n.w;
    const float rs = 1.f / sqrtf(1.f + 1e-5f);
    float gs0 = gamma[og + 0] * rs, gs1 = gamma[og + 1] * rs;
    float gs2 = gamma[og + 2] * rs, gs3 = gamma[og + 3] * rs;
    float bt0 = beta[og + 0], bt1 = beta[og + 1];
    float bt2 = beta[og + 2], bt3 = beta[og + 3];
    float b0 = -INFINITY, b1 = -INFINITY, b2 = -INFINITY, b3 = -INFINITY;
    #pragma unroll
    for (int kk = 0; kk < KNN; ++kk) {
        int nb = base_pt + sidx[p][kk];
        float4 ub = *(const float4*)&uv[(long)nb * NC + og];
        b0 = fmaxf(b0, lrelu((ub.x + c0) * gs0 + bt0));
        b1 = fmaxf(b1, lrelu((ub.y + c1) * gs1 + bt1));
        b2 = fmaxf(b2, lrelu((ub.z + c2) * gs2 + bt2));
        b3 = fmaxf(b3, lrelu((ub.w + c3) * gs3 + bt3));
    }
    float4 o4; o4.x = b0; o4.y = b1; o4.z = b2; o4.w = b3;
    *(float4*)&out[(long)g * 512 + outoff + og] = o4;
}

// ---------------- init h5 key buffer ----------------
__global__ void init_h5_kernel(unsigned* __restrict__ h5key) {
    int t = blockIdx.x * blockDim.x + threadIdx.x;
    if (t < BATCH * 1024) h5key[t] = 0u;
}

// ---------------- w5 GEMM + BN + lrelu + max over n ----------------
// 1D grid, XCD-swizzled: xcd = id&7 owns (batch = xcd>>1, o-half = xcd&1);
// slot n-tile-major so the 4 o-blocks sharing an A-tile are L2-co-resident.
__global__ __launch_bounds__(256) void w5max_kernel(
    const float* __restrict__ cat, const float* __restrict__ w5,
    const float* __restrict__ g5, const float* __restrict__ b5,
    unsigned* __restrict__ h5key) {
    __shared__ float As[16][132];
    __shared__ float Bs[16][132];
    int id = blockIdx.x;
    int xcd = id & 7, slot = id >> 3;
    int b = xcd >> 1;
    int o0 = (((xcd & 1) << 2) + (slot & 3)) * 128;
    int n0 = (slot >> 2) * 128;
    int tx = threadIdx.x & 15, ty = threadIdx.x >> 4;
    const float* A = cat + (long)b * N_PTS * 512;
    float acc[8][8] = {};
    for (int kt = 0; kt < 32; ++kt) {
        int k0 = kt * 16;
        for (int e = threadIdx.x; e < 2048; e += 256) {
            int kk = e & 15, r = e >> 4;
            As[kk][r] = A[(long)(n0 + r) * 512 + k0 + kk];
            Bs[kk][r] = w5[(long)(o0 + r) * 512 + k0 + kk];
        }
        __syncthreads();
        #pragma unroll
        for (int kk = 0; kk < 16; ++kk) {
            float a[8], bb[8];
            *(float4*)&a[0] = *(float4*)&As[kk][ty * 8];
            *(float4*)&a[4] = *(float4*)&As[kk][ty * 8 + 4];
            *(float4*)&bb[0] = *(float4*)&Bs[kk][tx * 4];
            *(float4*)&bb[4] = *(float4*)&Bs[kk][64 + tx * 4];
            #pragma unroll
            for (int i = 0; i < 8; ++i)
                #pragma unroll
                for (int j = 0; j < 8; ++j) acc[i][j] += a[i] * bb[j];
        }
        __syncthreads();
    }
    float colmax[8];
    #pragma unroll
    for (int j = 0; j < 8; ++j) {
        int col_local = (j < 4) ? (tx * 4 + j) : (64 + tx * 4 + (j - 4));
        int o = o0 + col_local;
        float gsc = g5[o] / sqrtf(1.f + 1e-5f);
        float bto = b5[o];
        float m = -INFINITY;
        #pragma unroll
        for (int i = 0; i < 8; ++i)
            m = fmaxf(m, lrelu(acc[i][j] * gsc + bto));
        colmax[j] = m;
    }
    __syncthreads();
    float* red = &As[0][0];
    #pragma unroll
    for (int j = 0; j < 8; ++j) {
        int col_local = (j < 4) ? (tx * 4 + j) : (64 + tx * 4 + (j - 4));
        red[ty * 128 + col_local] = colmax[j];
    }
    __syncthreads();
    if (threadIdx.x < 128) {
        int col = threadIdx.x;
        float m = -INFINITY;
        #pragma unroll
        for (int t = 0; t < 16; ++t) m = fmaxf(m, red[t * 128 + col]);
        atomicMax(&h5key[b * 1024 + o0 + col], f2key(m));
    }
}

// ---------------- FC head ----------------
__global__ void fc1_kernel(const unsigned* __restrict__ h5key,
                           const float* __restrict__ fw1,
                           const float* __restrict__ fg1,
                           const float* __restrict__ fbt1,
                           float* __restrict__ f1) {
    int o = blockIdx.x * 256 + threadIdx.x;
    int b = blockIdx.y;
    if (o >= 512) return;
    float s = 0.f;
    for (int c = 0; c < 1024; ++c)
        s += key2f(h5key[b * 1024 + c]) * fw1[o * 1024 + c];
    float h = s * (fg1[o] / sqrtf(1.f + 1e-5f)) + fbt1[o];
    f1[b * 512 + o] = lrelu(h);
}

__global__ void fc2_kernel(const float* __restrict__ f1,
                           const float* __restrict__ fw2,
                           const float* __restrict__ fb2,
                           const float* __restrict__ fg2,
                           const float* __restrict__ fbt2,
                           float* __restrict__ f2) {
    int o = threadIdx.x;
    int b = blockIdx.x;
    float s = fb2[o];
    for (int c = 0; c < 512; ++c) s += f1[b * 512 + c] * fw2[o * 512 + c];
    float h = s * (fg2[o] / sqrtf(1.f + 1e-5f)) + fbt2[o];
    f2[b * 256 + o] = lrelu(h);
}

__global__ void fc3_kernel(const float* __restrict__ f2,
                           const float* __restrict__ fw3,
                           const float* __restrict__ fb3,
                           float* __restrict__ out) {
    int t = threadIdx.x;
    if (t >= BATCH * 3) return;
    int b = t / 3, o = t - b * 3;
    float s = fb3[o];
    for (int c = 0; c < 256; ++c) s += f2[b * 256 + c] * fw3[o * 256 + c];
    out[t] = s;
}

extern "C" void kernel_launch(void* const* d_in, const int* in_sizes, int n_in,
                              void* d_out, int out_size, void* d_ws, size_t ws_size,
                              hipStream_t stream) {
    const float* points = (const float*)d_in[0];
    const float* w1 = (const float*)d_in[2];
    const float* g1 = (const float*)d_in[3];
    const float* b1 = (const float*)d_in[4];
    const float* w2 = (const float*)d_in[5];
    const float* g2 = (const float*)d_in[6];
    const float* b2 = (const float*)d_in[7];
    const float* w3 = (const float*)d_in[8];
    const float* g3 = (const float*)d_in[9];
    const float* b3 = (const float*)d_in[10];
    const float* w4 = (const float*)d_in[11];
    const float* g4 = (const float*)d_in[12];
    const float* b4 = (const float*)d_in[13];
    const float* w5 = (const float*)d_in[14];
    const float* g5 = (const float*)d_in[15];
    const float* b5 = (const float*)d_in[16];
    const float* fw1 = (const float*)d_in[17];
    const float* fg1 = (const float*)d_in[18];
    const float* fbt1 = (const float*)d_in[19];
    const float* fw2 = (const float*)d_in[20];
    const float* fb2 = (const float*)d_in[21];
    const float* fg2 = (const float*)d_in[22];
    const float* fbt2 = (const float*)d_in[23];
    const float* fw3 = (const float*)d_in[24];
    const float* fb3 = (const float*)d_in[25];

    float* ws = (float*)d_ws;
    float* cat = ws;                                     // 4*4096*512
    float* sq = cat + (long)BATCH * N_PTS * 512;         // 16384
    unsigned* h5key = (unsigned*)(sq + BATCH * N_PTS);   // 4096
    float* f1 = (float*)(h5key + BATCH * 1024);          // 2048
    float* f2 = f1 + BATCH * 512;                        // 1024
    int* idxbuf = (int*)(f2 + BATCH * 256);              // 4*4096*10
    float* uv = (float*)(idxbuf + (long)BATCH * N_PTS * KNN); // 4*4096*512
    float* pvb = uv + (long)BATCH * N_PTS * 512;         // 4*4096*4*11
    int* pib = (int*)(pvb + (long)BATCH * N_PTS * NCHUNK * 11);

    dim3 knng(N_PTS / 32, NCHUNK, BATCH);

    // layer 1: points(3) -> o1 (64) at cat+0
    sq_kernel<<<64, 256, 0, stream>>>(points, 3, 3, sq);
    knn_kernel<3, 3><<<knng, 256, 0, stream>>>(points, sq, pvb, pib);
    knnmerge_kernel<<<64, 256, 0, stream>>>(pvb, pib, idxbuf);
    edgeconv_kernel<3, 64, 16, 16><<<N_PTS * BATCH / 16, 256, 0, stream>>>(
        points, 3, idxbuf, w1, g1, b1, cat, 0);

    // layer 2: o1(64) -> o2 (64) at cat+64
    sq_kernel<<<64, 256, 0, stream>>>(cat + 0, 512, 64, sq);
    knn_kernel<64, 512><<<knng, 256, 0, stream>>>(cat + 0, sq, pvb, pib);
    knnmerge_kernel<<<64, 256, 0, stream>>>(pvb, pib, idxbuf);
    uvgemm_kernel<64, 64><<<dim3(1, 128), 256, 0, stream>>>(cat, 0, w2, uv);
    edgemax_kernel<64><<<1024, 256, 0, stream>>>(uv, idxbuf, g2, b2, cat, 64);

    // layer 3: o2(64) -> o3 (128) at cat+128
    sq_kernel<<<64, 256, 0, stream>>>(cat + 64, 512, 64, sq);
    knn_kernel<64, 512><<<knng, 256, 0, stream>>>(cat + 64, sq, pvb, pib);
    knnmerge_kernel<<<64, 256, 0, stream>>>(pvb, pib, idxbuf);
    uvgemm_kernel<64, 128><<<dim3(2, 128), 256, 0, stream>>>(cat, 64, w3, uv);
    edgemax_kernel<128><<<2048, 256, 0, stream>>>(uv, idxbuf, g3, b3, cat, 128);

    // layer 4: o3(128) -> o4 (256) at cat+256
    sq_kernel<<<64, 256, 0, stream>>>(cat + 128, 512, 128, sq);
    knn_kernel<128, 512><<<knng, 256, 0, stream>>>(cat + 128, sq, pvb, pib);
    knnmerge_kernel<<<64, 256, 0, stream>>>(pvb, pib, idxbuf);
    uvgemm_kernel<128, 256><<<dim3(4, 128), 256, 0, stream>>>(cat, 128, w4, uv);
    edgemax_kernel<256><<<4096, 256, 0, stream>>>(uv, idxbuf, g4, b4, cat, 256);

    // global feature
    init_h5_kernel<<<16, 256, 0, stream>>>(h5key);
    w5max_kernel<<<1024, 256, 0, stream>>>(cat, w5, g5, b5, h5key);

    // FC head
    fc1_kernel<<<dim3(2, BATCH), 256, 0, stream>>>(h5key, fw1, fg1, fbt1, f1);
    fc2_kernel<<<BATCH, 256, 0, stream>>>(f1, fw2, fb2, fg2, fbt2, f2);
    fc3_kernel<<<1, 64, 0, stream>>>(f2, fw3, fb3, (float*)d_out);
}

// Round 8
// 7385.786 us; speedup vs baseline: 3.3823x; 1.5905x over previous
//
#include <hip/hip_runtime.h>
#include <math.h>

#define N_PTS 4096
#define BATCH 4
#define KNN 10
#define NCHUNK 2
#define CHUNK 2048

__device__ __forceinline__ bool better(float v1, int i1, float v2, int i2) {
    return (v1 > v2) || (v1 == v2 && i1 < i2);
}

__device__ __forceinline__ unsigned f2key(float x) {
    unsigned u = __float_as_uint(x);
    return (u & 0x80000000u) ? ~u : (u | 0x80000000u);
}
__device__ __forceinline__ float key2f(unsigned k) {
    unsigned u = (k & 0x80000000u) ? (k & 0x7FFFFFFFu) : ~k;
    return __uint_as_float(u);
}

__device__ __forceinline__ float lrelu(float h) { return (h > 0.f) ? h : 0.2f * h; }

__device__ __forceinline__ void ins11(float v, int c, float (&lv)[11], int (&li)[11]) {
    if (better(v, c, lv[10], li[10])) {
        lv[10] = v; li[10] = c;
        #pragma unroll
        for (int j = 10; j > 0; --j) {
            if (better(lv[j], li[j], lv[j - 1], li[j - 1])) {
                float tv = lv[j]; lv[j] = lv[j - 1]; lv[j - 1] = tv;
                int ti = li[j]; li[j] = li[j - 1]; li[j - 1] = ti;
            }
        }
    }
}

// ---------------- squared norms ----------------
__global__ void sq_kernel(const float* __restrict__ x, int xstr, int D,
                          float* __restrict__ sq) {
    int g = blockIdx.x * blockDim.x + threadIdx.x;
    if (g >= BATCH * N_PTS) return;
    const float* row = x + (long)g * xstr;
    float s = 0.f;
    if ((D & 3) == 0) {
        for (int c = 0; c < D; c += 4) {
            float4 v = *(const float4*)&row[c];
            s += v.x * v.x + v.y * v.y + v.z * v.z + v.w * v.w;
        }
    } else {
        for (int c = 0; c < D; ++c) { float v = row[c]; s += v * v; }
    }
    sq[g] = s;
}

// ---------------- fused knn over a 2048-col chunk ----------------
// Round-5 mapping: thread = 2 rows x 8 cols (acc[2][8], 2 top-11 lists,
// proven no-spill at 76 VGPR). Single-buffered Bs, cols tx*4 / 64+tx*4
// (2-way aliasing = free). Fold straight from accumulators (no dt LDS
// round-trip). Grid = 128 row-blocks x 2 chunks x 4 batch = 1024 blocks
// -> 4 blocks/CU. 16-lane pop-merge emits sorted chunk top-11 to pv/pi.
template <int D, int XSTR>
__global__ __launch_bounds__(256) void knn_kernel(
    const float* __restrict__ x, const float* __restrict__ sq,
    float* __restrict__ pv, int* __restrict__ pi) {
    constexpr int KTOT = (D + 15) & ~15;
    constexpr int NKT = KTOT / 16;
    constexpr int ROWS = 32;
    constexpr int NCT = CHUNK / 128;
    __shared__ float As[KTOT][34];
    __shared__ float Bs[16][132];
    __shared__ float sqs[CHUNK];
    int b = blockIdx.z, chunk = blockIdx.y;
    int r0 = blockIdx.x * ROWS;
    int cbase = chunk * CHUNK;
    const float* xb = x + (long)b * N_PTS * XSTR;
    const float* sqb = sq + b * N_PTS;
    int tid = threadIdx.x;
    int tx = tid & 15, ty = tid >> 4;
    for (int e = tid; e < ROWS * KTOT; e += 256) {
        int kk = e % KTOT, row = e / KTOT;
        As[kk][row] = (kk < D) ? xb[(long)(r0 + row) * XSTR + kk] : 0.f;
    }
    for (int e = tid; e < CHUNK; e += 256) sqs[e] = sqb[cbase + e];
    float sqr0 = sqb[r0 + ty * 2 + 0];
    float sqr1 = sqb[r0 + ty * 2 + 1];
    float lv0[11], lv1[11]; int li0[11], li1[11];
    #pragma unroll
    for (int j = 0; j < 11; ++j) {
        lv0[j] = -INFINITY; lv1[j] = -INFINITY;
        li0[j] = 0x7FFFFFFF; li1[j] = 0x7FFFFFFF;
    }
    __syncthreads();
    #pragma unroll 1
    for (int ct = 0; ct < NCT; ++ct) {
        int c0 = cbase + ct * 128;
        float acc[2][8] = {};
        #pragma unroll 1
        for (int kt = 0; kt < NKT; ++kt) {
            int k0 = kt * 16;
            for (int e = tid; e < 2048; e += 256) {
                int kk = e & 15, col = e >> 4;
                int c = k0 + kk;
                Bs[kk][col] = (c < D) ? xb[(long)(c0 + col) * XSTR + c] : 0.f;
            }
            __syncthreads();
            #pragma unroll
            for (int kk = 0; kk < 16; ++kk) {
                float2 a2 = *(float2*)&As[k0 + kk][ty * 2];
                float bb[8];
                *(float4*)&bb[0] = *(float4*)&Bs[kk][tx * 4];
                *(float4*)&bb[4] = *(float4*)&Bs[kk][64 + tx * 4];
                #pragma unroll
                for (int j = 0; j < 8; ++j) {
                    acc[0][j] += a2.x * bb[j];
                    acc[1][j] += a2.y * bb[j];
                }
            }
            __syncthreads();
        }
        // fold this ct's 16 candidates (register-only, both rows)
        int ctoff = ct * 128;
        #pragma unroll
        for (int j = 0; j < 4; ++j) {
            int cl0 = ctoff + tx * 4 + j;
            int cl1 = ctoff + 64 + tx * 4 + j;
            float sc0 = sqs[cl0], sc1 = sqs[cl1];
            ins11(2.f * acc[0][j] - sqr0 - sc0, cbase + cl0, lv0, li0);
            ins11(2.f * acc[0][4 + j] - sqr0 - sc1, cbase + cl1, lv0, li0);
            ins11(2.f * acc[1][j] - sqr1 - sc0, cbase + cl0, lv1, li1);
            ins11(2.f * acc[1][4 + j] - sqr1 - sc1, cbase + cl1, lv1, li1);
        }
    }
    // 16-lane pop-merge (round-5 proven): slot tx of the sorted chunk list
    float rv0 = 0.f, rv1 = 0.f; int ri0 = 0, ri1 = 0;
    #pragma unroll
    for (int r = 0; r < 11; ++r) {
        float bv = lv0[0]; int bi = li0[0];
        #pragma unroll
        for (int off = 8; off > 0; off >>= 1) {
            float ov = __shfl_xor(bv, off);
            int oi = __shfl_xor(bi, off);
            if (better(ov, oi, bv, bi)) { bv = ov; bi = oi; }
        }
        if (li0[0] == bi) {
            #pragma unroll
            for (int j = 0; j < 10; ++j) { lv0[j] = lv0[j + 1]; li0[j] = li0[j + 1]; }
            lv0[10] = -INFINITY; li0[10] = 0x7FFFFFFF;
        }
        if (tx == r) { rv0 = bv; ri0 = bi; }
    }
    #pragma unroll
    for (int r = 0; r < 11; ++r) {
        float bv = lv1[0]; int bi = li1[0];
        #pragma unroll
        for (int off = 8; off > 0; off >>= 1) {
            float ov = __shfl_xor(bv, off);
            int oi = __shfl_xor(bi, off);
            if (better(ov, oi, bv, bi)) { bv = ov; bi = oi; }
        }
        if (li1[0] == bi) {
            #pragma unroll
            for (int j = 0; j < 10; ++j) { lv1[j] = lv1[j + 1]; li1[j] = li1[j + 1]; }
            lv1[10] = -INFINITY; li1[10] = 0x7FFFFFFF;
        }
        if (tx == r) { rv1 = bv; ri1 = bi; }
    }
    if (tx < 11) {
        long row0 = (long)b * N_PTS + r0 + ty * 2;
        long o0 = (row0 * NCHUNK + chunk) * 11 + tx;
        long o1 = ((row0 + 1) * NCHUNK + chunk) * 11 + tx;
        pv[o0] = rv0; pi[o0] = ri0;
        pv[o1] = rv1; pi[o1] = ri1;
    }
}

// ---------------- merge sorted chunk lists -> exact global top-11 ---------
__global__ void knnmerge_kernel(const float* __restrict__ pv,
                                const int* __restrict__ pi,
                                int* __restrict__ idxout) {
    int row = blockIdx.x * blockDim.x + threadIdx.x;
    if (row >= BATCH * N_PTS) return;
    const float* v = pv + (long)row * (NCHUNK * 11);
    const int* ii = pi + (long)row * (NCHUNK * 11);
    float hv[NCHUNK]; int hi[NCHUNK]; int hp[NCHUNK];
    #pragma unroll
    for (int c = 0; c < NCHUNK; ++c) {
        hp[c] = 0; hv[c] = v[c * 11]; hi[c] = ii[c * 11];
    }
    #pragma unroll
    for (int t = 0; t < 11; ++t) {
        int cb = 0; float bv = hv[0]; int bi = hi[0];
        #pragma unroll
        for (int c = 1; c < NCHUNK; ++c)
            if (better(hv[c], hi[c], bv, bi)) { cb = c; bv = hv[c]; bi = hi[c]; }
        if (t > 0) idxout[(long)row * KNN + (t - 1)] = bi;
        if (t < 10) {
            int np = ++hp[cb];
            hv[cb] = v[cb * 11 + np]; hi[cb] = ii[cb * 11 + np];
        }
    }
}

// ---------------- edge conv L1 (DIN=3, fused path) ----------------
template <int DIN, int DOUT, int PTS, int TPP>
__global__ __launch_bounds__(256) void edgeconv_kernel(
    const float* __restrict__ x, int xstr, const int* __restrict__ idx,
    const float* __restrict__ w, const float* __restrict__ gamma,
    const float* __restrict__ beta, float* __restrict__ out, int outoff) {
    constexpr int DP = DIN + 1;
    constexpr int C2 = 2 * DIN;
    __shared__ float ctr[PTS][DP];
    __shared__ float nm[PTS][KNN][DP];
    int p0 = blockIdx.x * PTS;
    for (int e = threadIdx.x; e < PTS * DIN; e += 256) {
        int p = e / DIN, c = e - p * DIN;
        ctr[p][c] = x[(long)(p0 + p) * xstr + c];
    }
    __syncthreads();
    for (int e = threadIdx.x; e < PTS * KNN * DIN; e += 256) {
        int p = e / (KNN * DIN);
        int rem = e - p * (KNN * DIN);
        int kk = rem / DIN, c = rem - kk * DIN;
        int g = p0 + p;
        int nb = (g & ~(N_PTS - 1)) + idx[(long)g * KNN + kk];
        nm[p][kk][c] = x[(long)nb * xstr + c] - ctr[p][c];
    }
    __syncthreads();
    int p = threadIdx.x / TPP;
    int og = (threadIdx.x % TPP) * 4;
    float gs[4], bt[4];
    #pragma unroll
    for (int j = 0; j < 4; ++j) {
        gs[j] = gamma[og + j] / sqrtf(1.f + 1e-5f);
        bt[j] = beta[og + j];
    }
    float base[4] = {0.f, 0.f, 0.f, 0.f};
    for (int c = 0; c < DIN; ++c) {
        float cv = ctr[p][c];
        #pragma unroll
        for (int j = 0; j < 4; ++j) base[j] += cv * w[(og + j) * C2 + DIN + c];
    }
    float acc[KNN][4];
    #pragma unroll
    for (int kk = 0; kk < KNN; ++kk)
        #pragma unroll
        for (int j = 0; j < 4; ++j) acc[kk][j] = base[j];
    for (int c = 0; c < DIN; ++c) {
        float w4[4];
        #pragma unroll
        for (int j = 0; j < 4; ++j) w4[j] = w[(og + j) * C2 + c];
        #pragma unroll
        for (int kk = 0; kk < KNN; ++kk) {
            float nv = nm[p][kk][c];
            #pragma unroll
            for (int j = 0; j < 4; ++j) acc[kk][j] += nv * w4[j];
        }
    }
    float best[4] = {-INFINITY, -INFINITY, -INFINITY, -INFINITY};
    #pragma unroll
    for (int kk = 0; kk < KNN; ++kk)
        #pragma unroll
        for (int j = 0; j < 4; ++j)
            best[j] = fmaxf(best[j], lrelu(acc[kk][j] * gs[j] + bt[j]));
    #pragma unroll
    for (int j = 0; j < 4; ++j)
        out[(long)(p0 + p) * 512 + outoff + og + j] = best[j];
}

// ---------------- uv GEMM: uv[r][j] = sum_k x[r][k] * Bcat[k][j] ----------
template <int DIN, int DOUT>
__global__ __launch_bounds__(256) void uvgemm_kernel(
    const float* __restrict__ x, int xoff, const float* __restrict__ w,
    float* __restrict__ uv) {
    constexpr int NC = 2 * DOUT;
    __shared__ float As[16][132];
    __shared__ float Bs[16][132];
    int r0 = blockIdx.y * 128;
    int c0 = blockIdx.x * 128;
    int tx = threadIdx.x & 15, ty = threadIdx.x >> 4;
    float acc[8][8] = {};
    #pragma unroll 1
    for (int kt = 0; kt < DIN / 16; ++kt) {
        int k0 = kt * 16;
        for (int e = threadIdx.x; e < 2048; e += 256) {
            int kk = e & 15, r = e >> 4;
            As[kk][r] = x[(long)(r0 + r) * 512 + xoff + k0 + kk];
            int jg = c0 + r;
            Bs[kk][r] = (jg < DOUT) ? w[(long)jg * (2 * DIN) + k0 + kk]
                                    : w[(long)(jg - DOUT) * (2 * DIN) + DIN + k0 + kk];
        }
        __syncthreads();
        #pragma unroll
        for (int kk = 0; kk < 16; ++kk) {
            float a[8], bb[8];
            *(float4*)&a[0] = *(float4*)&As[kk][ty * 8];
            *(float4*)&a[4] = *(float4*)&As[kk][ty * 8 + 4];
            *(float4*)&bb[0] = *(float4*)&Bs[kk][tx * 4];
            *(float4*)&bb[4] = *(float4*)&Bs[kk][64 + tx * 4];
            #pragma unroll
            for (int i = 0; i < 8; ++i)
                #pragma unroll
                for (int j = 0; j < 8; ++j) acc[i][j] += a[i] * bb[j];
        }
        __syncthreads();
    }
    int cb0 = c0 + tx * 4;
    int cb1 = c0 + 64 + tx * 4;
    #pragma unroll
    for (int i = 0; i < 8; ++i) {
        int r = r0 + ty * 8 + i;
        *(float4*)&uv[(long)r * NC + cb0] = *(float4*)&acc[i][0];
        *(float4*)&uv[(long)r * NC + cb1] = *(float4*)&acc[i][4];
    }
}

// ---------------- edge max epilogue: h = u[nb] - u[n] + v[n] --------------
template <int DOUT>
__global__ __launch_bounds__(256) void edgemax_kernel(
    const float* __restrict__ uv, const int* __restrict__ idx,
    const float* __restrict__ gamma, const float* __restrict__ beta,
    float* __restrict__ out, int outoff) {
    constexpr int NC = 2 * DOUT;
    constexpr int TPP = DOUT / 4;
    constexpr int TP = 256 / TPP;
    __shared__ int sidx[TP][KNN];
    int p0 = blockIdx.x * TP;
    for (int e = threadIdx.x; e < TP * KNN; e += 256)
        sidx[e / KNN][e % KNN] = idx[(long)(p0 + e / KNN) * KNN + (e % KNN)];
    __syncthreads();
    int p = threadIdx.x / TPP;
    int og = (threadIdx.x % TPP) * 4;
    int g = p0 + p;
    int base_pt = g & ~(N_PTS - 1);
    const float* rowg = uv + (long)g * NC;
    float4 u_n = *(const float4*)&rowg[og];
    float4 v_n = *(const float4*)&rowg[DOUT + og];
    float c0 = v_n.x - u_n.x, c1 = v_n.y - u_n.y;
    float c2 = v_n.z - u_n.z, c3 = v_n.w - u_n.w;
    const float rs = 1.f / sqrtf(1.f + 1e-5f);
    float gs0 = gamma[og + 0] * rs, gs1 = gamma[og + 1] * rs;
    float gs2 = gamma[og + 2] * rs, gs3 = gamma[og + 3] * rs;
    float bt0 = beta[og + 0], bt1 = beta[og + 1];
    float bt2 = beta[og + 2], bt3 = beta[og + 3];
    float b0 = -INFINITY, b1 = -INFINITY, b2 = -INFINITY, b3 = -INFINITY;
    #pragma unroll
    for (int kk = 0; kk < KNN; ++kk) {
        int nb = base_pt + sidx[p][kk];
        float4 ub = *(const float4*)&uv[(long)nb * NC + og];
        b0 = fmaxf(b0, lrelu((ub.x + c0) * gs0 + bt0));
        b1 = fmaxf(b1, lrelu((ub.y + c1) * gs1 + bt1));
        b2 = fmaxf(b2, lrelu((ub.z + c2) * gs2 + bt2));
        b3 = fmaxf(b3, lrelu((ub.w + c3) * gs3 + bt3));
    }
    float4 o4; o4.x = b0; o4.y = b1; o4.z = b2; o4.w = b3;
    *(float4*)&out[(long)g * 512 + outoff + og] = o4;
}

// ---------------- init h5 key buffer ----------------
__global__ void init_h5_kernel(unsigned* __restrict__ h5key) {
    int t = blockIdx.x * blockDim.x + threadIdx.x;
    if (t < BATCH * 1024) h5key[t] = 0u;
}

// ---------------- w5 GEMM + BN + lrelu + max over n ----------------
__global__ __launch_bounds__(256) void w5max_kernel(
    const float* __restrict__ cat, const float* __restrict__ w5,
    const float* __restrict__ g5, const float* __restrict__ b5,
    unsigned* __restrict__ h5key) {
    __shared__ float As[16][132];
    __shared__ float Bs[16][132];
    int id = blockIdx.x;
    int xcd = id & 7, slot = id >> 3;
    int b = xcd >> 1;
    int o0 = (((xcd & 1) << 2) + (slot & 3)) * 128;
    int n0 = (slot >> 2) * 128;
    int tx = threadIdx.x & 15, ty = threadIdx.x >> 4;
    const float* A = cat + (long)b * N_PTS * 512;
    float acc[8][8] = {};
    for (int kt = 0; kt < 32; ++kt) {
        int k0 = kt * 16;
        for (int e = threadIdx.x; e < 2048; e += 256) {
            int kk = e & 15, r = e >> 4;
            As[kk][r] = A[(long)(n0 + r) * 512 + k0 + kk];
            Bs[kk][r] = w5[(long)(o0 + r) * 512 + k0 + kk];
        }
        __syncthreads();
        #pragma unroll
        for (int kk = 0; kk < 16; ++kk) {
            float a[8], bb[8];
            *(float4*)&a[0] = *(float4*)&As[kk][ty * 8];
            *(float4*)&a[4] = *(float4*)&As[kk][ty * 8 + 4];
            *(float4*)&bb[0] = *(float4*)&Bs[kk][tx * 4];
            *(float4*)&bb[4] = *(float4*)&Bs[kk][64 + tx * 4];
            #pragma unroll
            for (int i = 0; i < 8; ++i)
                #pragma unroll
                for (int j = 0; j < 8; ++j) acc[i][j] += a[i] * bb[j];
        }
        __syncthreads();
    }
    float colmax[8];
    #pragma unroll
    for (int j = 0; j < 8; ++j) {
        int col_local = (j < 4) ? (tx * 4 + j) : (64 + tx * 4 + (j - 4));
        int o = o0 + col_local;
        float gsc = g5[o] / sqrtf(1.f + 1e-5f);
        float bto = b5[o];
        float m = -INFINITY;
        #pragma unroll
        for (int i = 0; i < 8; ++i)
            m = fmaxf(m, lrelu(acc[i][j] * gsc + bto));
        colmax[j] = m;
    }
    __syncthreads();
    float* red = &As[0][0];
    #pragma unroll
    for (int j = 0; j < 8; ++j) {
        int col_local = (j < 4) ? (tx * 4 + j) : (64 + tx * 4 + (j - 4));
        red[ty * 128 + col_local] = colmax[j];
    }
    __syncthreads();
    if (threadIdx.x < 128) {
        int col = threadIdx.x;
        float m = -INFINITY;
        #pragma unroll
        for (int t = 0; t < 16; ++t) m = fmaxf(m, red[t * 128 + col]);
        atomicMax(&h5key[b * 1024 + o0 + col], f2key(m));
    }
}

// ---------------- FC head ----------------
__global__ void fc1_kernel(const unsigned* __restrict__ h5key,
                           const float* __restrict__ fw1,
                           const float* __restrict__ fg1,
                           const float* __restrict__ fbt1,
                           float* __restrict__ f1) {
    int o = blockIdx.x * 256 + threadIdx.x;
    int b = blockIdx.y;
    if (o >= 512) return;
    float s = 0.f;
    for (int c = 0; c < 1024; ++c)
        s += key2f(h5key[b * 1024 + c]) * fw1[o * 1024 + c];
    float h = s * (fg1[o] / sqrtf(1.f + 1e-5f)) + fbt1[o];
    f1[b * 512 + o] = lrelu(h);
}

__global__ void fc2_kernel(const float* __restrict__ f1,
                           const float* __restrict__ fw2,
                           const float* __restrict__ fb2,
                           const float* __restrict__ fg2,
                           const float* __restrict__ fbt2,
                           float* __restrict__ f2) {
    int o = threadIdx.x;
    int b = blockIdx.x;
    float s = fb2[o];
    for (int c = 0; c < 512; ++c) s += f1[b * 512 + c] * fw2[o * 512 + c];
    float h = s * (fg2[o] / sqrtf(1.f + 1e-5f)) + fbt2[o];
    f2[b * 256 + o] = lrelu(h);
}

__global__ void fc3_kernel(const float* __restrict__ f2,
                           const float* __restrict__ fw3,
                           const float* __restrict__ fb3,
                           float* __restrict__ out) {
    int t = threadIdx.x;
    if (t >= BATCH * 3) return;
    int b = t / 3, o = t - b * 3;
    float s = fb3[o];
    for (int c = 0; c < 256; ++c) s += f2[b * 256 + c] * fw3[o * 256 + c];
    out[t] = s;
}

extern "C" void kernel_launch(void* const* d_in, const int* in_sizes, int n_in,
                              void* d_out, int out_size, void* d_ws, size_t ws_size,
                              hipStream_t stream) {
    const float* points = (const float*)d_in[0];
    const float* w1 = (const float*)d_in[2];
    const float* g1 = (const float*)d_in[3];
    const float* b1 = (const float*)d_in[4];
    const float* w2 = (const float*)d_in[5];
    const float* g2 = (const float*)d_in[6];
    const float* b2 = (const float*)d_in[7];
    const float* w3 = (const float*)d_in[8];
    const float* g3 = (const float*)d_in[9];
    const float* b3 = (const float*)d_in[10];
    const float* w4 = (const float*)d_in[11];
    const float* g4 = (const float*)d_in[12];
    const float* b4 = (const float*)d_in[13];
    const float* w5 = (const float*)d_in[14];
    const float* g5 = (const float*)d_in[15];
    const float* b5 = (const float*)d_in[16];
    const float* fw1 = (const float*)d_in[17];
    const float* fg1 = (const float*)d_in[18];
    const float* fbt1 = (const float*)d_in[19];
    const float* fw2 = (const float*)d_in[20];
    const float* fb2 = (const float*)d_in[21];
    const float* fg2 = (const float*)d_in[22];
    const float* fbt2 = (const float*)d_in[23];
    const float* fw3 = (const float*)d_in[24];
    const float* fb3 = (const float*)d_in[25];

    float* ws = (float*)d_ws;
    float* cat = ws;                                     // 4*4096*512
    float* sq = cat + (long)BATCH * N_PTS * 512;         // 16384
    unsigned* h5key = (unsigned*)(sq + BATCH * N_PTS);   // 4096
    float* f1 = (float*)(h5key + BATCH * 1024);          // 2048
    float* f2 = f1 + BATCH * 512;                        // 1024
    int* idxbuf = (int*)(f2 + BATCH * 256);              // 4*4096*10
    float* uv = (float*)(idxbuf + (long)BATCH * N_PTS * KNN); // 4*4096*512
    float* pvb = uv + (long)BATCH * N_PTS * 512;         // 4*4096*2*11
    int* pib = (int*)(pvb + (long)BATCH * N_PTS * NCHUNK * 11);

    dim3 knng(N_PTS / 32, NCHUNK, BATCH);   // 1024 blocks

    // layer 1: points(3) -> o1 (64) at cat+0
    sq_kernel<<<64, 256, 0, stream>>>(points, 3, 3, sq);
    knn_kernel<3, 3><<<knng, 256, 0, stream>>>(points, sq, pvb, pib);
    knnmerge_kernel<<<64, 256, 0, stream>>>(pvb, pib, idxbuf);
    edgeconv_kernel<3, 64, 16, 16><<<N_PTS * BATCH / 16, 256, 0, stream>>>(
        points, 3, idxbuf, w1, g1, b1, cat, 0);

    // layer 2: o1(64) -> o2 (64) at cat+64
    sq_kernel<<<64, 256, 0, stream>>>(cat + 0, 512, 64, sq);
    knn_kernel<64, 512><<<knng, 256, 0, stream>>>(cat + 0, sq, pvb, pib);
    knnmerge_kernel<<<64, 256, 0, stream>>>(pvb, pib, idxbuf);
    uvgemm_kernel<64, 64><<<dim3(1, 128), 256, 0, stream>>>(cat, 0, w2, uv);
    edgemax_kernel<64><<<1024, 256, 0, stream>>>(uv, idxbuf, g2, b2, cat, 64);

    // layer 3: o2(64) -> o3 (128) at cat+128
    sq_kernel<<<64, 256, 0, stream>>>(cat + 64, 512, 64, sq);
    knn_kernel<64, 512><<<knng, 256, 0, stream>>>(cat + 64, sq, pvb, pib);
    knnmerge_kernel<<<64, 256, 0, stream>>>(pvb, pib, idxbuf);
    uvgemm_kernel<64, 128><<<dim3(2, 128), 256, 0, stream>>>(cat, 64, w3, uv);
    edgemax_kernel<128><<<2048, 256, 0, stream>>>(uv, idxbuf, g3, b3, cat, 128);

    // layer 4: o3(128) -> o4 (256) at cat+256
    sq_kernel<<<64, 256, 0, stream>>>(cat + 128, 512, 128, sq);
    knn_kernel<128, 512><<<knng, 256, 0, stream>>>(cat + 128, sq, pvb, pib);
    knnmerge_kernel<<<64, 256, 0, stream>>>(pvb, pib, idxbuf);
    uvgemm_kernel<128, 256><<<dim3(4, 128), 256, 0, stream>>>(cat, 128, w4, uv);
    edgemax_kernel<256><<<4096, 256, 0, stream>>>(uv, idxbuf, g4, b4, cat, 256);

    // global feature
    init_h5_kernel<<<16, 256, 0, stream>>>(h5key);
    w5max_kernel<<<1024, 256, 0, stream>>>(cat, w5, g5, b5, h5key);

    // FC head
    fc1_kernel<<<dim3(2, BATCH), 256, 0, stream>>>(h5key, fw1, fg1, fbt1, f1);
    fc2_kernel<<<BATCH, 256, 0, stream>>>(f1, fw2, fb2, fg2, fbt2, f2);
    fc3_kernel<<<1, 64, 0, stream>>>(f2, fw3, fb3, (float*)d_out);
}